// Round 1
// baseline (218.011 us; speedup 1.0000x reference)
//
#include <hip/hip_runtime.h>
#include <math.h>

#define NPTS 2048
#define BLOCK 256

// One block per batch element. Each thread loads 4 whole points (12 floats =
// 3 x float4) per iteration, 2 iterations -> 2048 points/block.
// 17 accumulators: 0-2 sum(p), 3-5 sum(c), 6 sum|p|^2, 7 sum|c|^2,
// 8-16 sum p_j * c_k (row-major 3x3).
__global__ __launch_bounds__(BLOCK) void kabsch_kernel(
    const float* __restrict__ P, const float* __restrict__ C,
    float* __restrict__ out, int B) {
  const int b = blockIdx.x;
  const int t = threadIdx.x;
  const float4* p4 = (const float4*)(P + (size_t)b * (NPTS * 3));
  const float4* c4 = (const float4*)(C + (size_t)b * (NPTS * 3));

  float acc[17];
#pragma unroll
  for (int i = 0; i < 17; i++) acc[i] = 0.f;

#pragma unroll
  for (int k = 0; k < (NPTS * 3 / 4) / (BLOCK * 3); k++) {  // = 2 iterations
    const int base = k * (BLOCK * 3) + 3 * t;
    const float4 pa = p4[base], pb = p4[base + 1], pq = p4[base + 2];
    const float4 ca = c4[base], cb = c4[base + 1], cq = c4[base + 2];
    // de-interleave 12 floats -> 4 points (x,y,z)
    const float Px[4] = {pa.x, pa.w, pb.z, pq.y};
    const float Py[4] = {pa.y, pb.x, pb.w, pq.z};
    const float Pz[4] = {pa.z, pb.y, pq.x, pq.w};
    const float Cx[4] = {ca.x, ca.w, cb.z, cq.y};
    const float Cy[4] = {ca.y, cb.x, cb.w, cq.z};
    const float Cz[4] = {ca.z, cb.y, cq.x, cq.w};
#pragma unroll
    for (int i = 0; i < 4; i++) {
      const float px = Px[i], py = Py[i], pz = Pz[i];
      const float cx = Cx[i], cy = Cy[i], cz = Cz[i];
      acc[0] += px; acc[1] += py; acc[2] += pz;
      acc[3] += cx; acc[4] += cy; acc[5] += cz;
      acc[6] += px * px + py * py + pz * pz;
      acc[7] += cx * cx + cy * cy + cz * cz;
      acc[8]  += px * cx; acc[9]  += px * cy; acc[10] += px * cz;
      acc[11] += py * cx; acc[12] += py * cy; acc[13] += py * cz;
      acc[14] += pz * cx; acc[15] += pz * cy; acc[16] += pz * cz;
    }
  }

  // wave (64-lane) butterfly reduce, then cross-wave via LDS
#pragma unroll
  for (int off = 32; off > 0; off >>= 1) {
#pragma unroll
    for (int i = 0; i < 17; i++) acc[i] += __shfl_down(acc[i], off);
  }
  __shared__ float red[BLOCK / 64][17];
  const int wave = t >> 6, lane = t & 63;
  if (lane == 0) {
#pragma unroll
    for (int i = 0; i < 17; i++) red[wave][i] = acc[i];
  }
  __syncthreads();

  if (t == 0) {
    double s[17];
#pragma unroll
    for (int i = 0; i < 17; i++) {
      float v = red[0][i];
      for (int w = 1; w < BLOCK / 64; w++) v += red[w][i];
      s[i] = (double)v;
    }
    const double invN = 1.0 / (double)NPTS;
    const double spx = s[0], spy = s[1], spz = s[2];
    const double scx = s[3], scy = s[4], scz = s[5];
    const double Ep = s[6] - (spx * spx + spy * spy + spz * spz) * invN;
    const double Ec = s[7] - (scx * scx + scy * scy + scz * scz) * invN;
    // centered cross-covariance A (3x3)
    const double a00 = s[8]  - spx * scx * invN, a01 = s[9]  - spx * scy * invN, a02 = s[10] - spx * scz * invN;
    const double a10 = s[11] - spy * scx * invN, a11 = s[12] - spy * scy * invN, a12 = s[13] - spy * scz * invN;
    const double a20 = s[14] - spz * scx * invN, a21 = s[15] - spz * scy * invN, a22 = s[16] - spz * scz * invN;
    const double det = a00 * (a11 * a22 - a12 * a21)
                     - a01 * (a10 * a22 - a12 * a20)
                     + a02 * (a10 * a21 - a11 * a20);
    // Gram matrix G = A^T A (symmetric PSD); singular values = sqrt(eig(G))
    const double b00 = a00 * a00 + a10 * a10 + a20 * a20;
    const double b11 = a01 * a01 + a11 * a11 + a21 * a21;
    const double b22 = a02 * a02 + a12 * a12 + a22 * a22;
    const double b01 = a00 * a01 + a10 * a11 + a20 * a21;
    const double b02 = a00 * a02 + a10 * a12 + a20 * a22;
    const double b12 = a01 * a02 + a11 * a12 + a21 * a22;
    const double q = (b00 + b11 + b22) / 3.0;
    const double p1 = b01 * b01 + b02 * b02 + b12 * b12;
    const double d0 = b00 - q, d1 = b11 - q, d2 = b22 - q;
    const double p2 = d0 * d0 + d1 * d1 + d2 * d2 + 2.0 * p1;
    double e1, e2, e3;
    if (p2 < 1e-30) {
      e1 = e2 = e3 = q;
    } else {
      const double pp = sqrt(p2 / 6.0);
      const double inv = 1.0 / pp;
      const double c00 = d0 * inv, c11 = d1 * inv, c22 = d2 * inv;
      const double c01 = b01 * inv, c02 = b02 * inv, c12 = b12 * inv;
      double r = 0.5 * (c00 * (c11 * c22 - c12 * c12)
                      - c01 * (c01 * c22 - c12 * c02)
                      + c02 * (c01 * c12 - c11 * c02));
      r = fmin(1.0, fmax(-1.0, r));
      const double phi = acos(r) / 3.0;
      e1 = q + 2.0 * pp * cos(phi);
      e3 = q + 2.0 * pp * cos(phi + 2.0943951023931953);  // +2*pi/3 -> smallest
      e2 = 3.0 * q - e1 - e3;
    }
    const double s1 = sqrt(fmax(e1, 0.0));
    const double s2 = sqrt(fmax(e2, 0.0));
    const double s3 = sqrt(fmax(e3, 0.0));
    const double dsign = (det > 0.0) ? 1.0 : ((det < 0.0) ? -1.0 : 0.0);
    const double trRS = s1 + s2 + dsign * s3;  // tr(R A^T)
    const double msd = (Ep + Ec - 2.0 * trRS) * invN;
    const double rmsd = sqrt(fmax(msd, 0.0));
    atomicAdd(out, (float)(rmsd / (double)B));
  }
}

extern "C" void kernel_launch(void* const* d_in, const int* in_sizes, int n_in,
                              void* d_out, int out_size, void* d_ws, size_t ws_size,
                              hipStream_t stream) {
  const float* P = (const float*)d_in[0];
  const float* C = (const float*)d_in[1];
  float* out = (float*)d_out;
  const int B = in_sizes[0] / (NPTS * 3);
  hipMemsetAsync(out, 0, sizeof(float), stream);  // d_out is poisoned 0xAA before every call
  kabsch_kernel<<<B, BLOCK, 0, stream>>>(P, C, out, B);
}